// Round 2
// baseline (587.433 us; speedup 1.0000x reference)
//
#include <hip/hip_runtime.h>

#define SN 6400      // H*W
#define CN 256       // channels (= GEMM K)
#define NBATCH 2
#define NTILES 50    // SN / 128 (fixed-side row tiles)
#define NCHUNK 5     // streamed-side chunks
#define TPC 10       // 128-wide streamed tiles per chunk (grid = 50*5*2 = 500, 2/CU)

typedef _Float16 f16;
typedef f16 f16x8 __attribute__((ext_vector_type(8)));
typedef f16 f16x4 __attribute__((ext_vector_type(4)));
typedef float f32x4 __attribute__((ext_vector_type(4)));

__device__ __forceinline__ void gld16(const f16* g, f16* l) {
    __builtin_amdgcn_global_load_lds(
        (__attribute__((address_space(1))) void*)(g),
        (__attribute__((address_space(3))) void*)(l), 16, 0, 0);
}

// Stage a 128-row x 64-half (16 KB) K-chunk into LDS (256 threads).
// LDS row = 64 halfs = 128 B = 8 x 16B chunks. Chunk at LDS position c holds
// global chunk c ^ (row&7) (swizzle on the SOURCE address; DMA lane->LDS map
// is fixed: wave-uniform base + lane*16B). Verified conflict-free.
__device__ __forceinline__ void stage64(const f16* __restrict__ gbase,
                                        f16* lbase, int tid) {
    #pragma unroll
    for (int it = 0; it < 4; ++it) {
        int q = it * 256 + tid;
        int row = q >> 3, c = q & 7;
        int cg = c ^ (row & 7);
        gld16(gbase + (size_t)row * CN + cg * 8,
              lbase + (size_t)(q & ~63) * 8);
    }
}

// ---------------- prep kernels (unchanged) ----------------

__global__ __launch_bounds__(256) void k_meanT(const float* __restrict__ T,
                                               float* __restrict__ meanT) {
    int c = blockIdx.x, t = threadIdx.x;
    const float* p0 = T + (size_t)c * SN;
    const float* p1 = T + (size_t)(CN + c) * SN;
    float s = 0.f;
    for (int i = t; i < SN; i += 256) s += p0[i] + p1[i];
    #pragma unroll
    for (int d = 1; d < 64; d <<= 1) s += __shfl_xor(s, d, 64);
    __shared__ float sb[4];
    if ((t & 63) == 0) sb[t >> 6] = s;
    __syncthreads();
    if (t == 0) meanT[c] = (sb[0] + sb[1] + sb[2] + sb[3]) * (1.0f / 12800.0f);
}

// transpose [n,c,s] -> [n,s,c], center, cast to fp16 (normalized by k_nrm)
__global__ __launch_bounds__(256) void k_xpose(const float* __restrict__ X,
                                               const float* __restrict__ meanT,
                                               f16* __restrict__ out) {
    int n = blockIdx.z, c0 = blockIdx.y * 32, s0 = blockIdx.x * 64;
    __shared__ float tile[32][65];
    int tx = threadIdx.x & 63, ty = threadIdx.x >> 6;
    const float* Xb = X + ((size_t)n * CN + c0) * SN + s0;
    #pragma unroll
    for (int cy = ty; cy < 32; cy += 4)
        tile[cy][tx] = Xb[(size_t)cy * SN + tx] - meanT[c0 + cy];
    __syncthreads();
    int cc = threadIdx.x & 31, sy = threadIdx.x >> 5;
    f16* ob = out + ((size_t)n * SN + s0) * CN + c0;
    #pragma unroll
    for (int sr = sy; sr < 64; sr += 8)
        ob[(size_t)sr * CN + cc] = (f16)tile[cc][sr];
}

// fused: per-row sum-of-squares -> rsqrt -> in-place scale (one wave per row)
__global__ __launch_bounds__(256) void k_nrm(f16* __restrict__ Ah,
                                             f16* __restrict__ Bh) {
    int w = threadIdx.x >> 6, lane = threadIdx.x & 63;
    int idx = blockIdx.x * 4 + w;
    f16x4* pa = (f16x4*)(Ah + (size_t)idx * CN + lane * 4);
    f16x4* pb = (f16x4*)(Bh + (size_t)idx * CN + lane * 4);
    f16x4 a = *pa, b = *pb;
    float sa = 0.f, sb = 0.f;
    #pragma unroll
    for (int j = 0; j < 4; ++j) {
        float x = (float)a[j]; sa += x * x;
        float y = (float)b[j]; sb += y * y;
    }
    #pragma unroll
    for (int d = 1; d < 64; d <<= 1) {
        sa += __shfl_xor(sa, d, 64);
        sb += __shfl_xor(sb, d, 64);
    }
    float ra = rsqrtf(sa), rb = rsqrtf(sb);
    #pragma unroll
    for (int j = 0; j < 4; ++j) {
        a[j] = (f16)((float)a[j] * ra);
        b[j] = (f16)((float)b[j] * rb);
    }
    *pa = a; *pb = b;
}

// ---------------- fused GEMM passes ----------------
// Barrier-free K-loop structure: 256 threads (4 waves), tile = 128 fixed rows
// x 128 streamed cols per inner step. A tile (128x256 halfs, 64 KB) staged
// once into LDS (read-only afterwards -> NO barriers in the K-loop; races
// impossible). B operand is partitioned disjointly across waves (wave wc owns
// streamed rows wc*32..wc*32+31) and loaded GLOBAL->REGISTER directly in MFMA
// fragment layout, register-double-buffered one 64-K-half ahead (compile-time
// E/O naming). Compiler handles counted vmcnt; no vmcnt(0) drains anywhere.
// LDS 66 KB -> 2 blocks/CU; grid 500 = exactly 2/CU, one residency round.
// PASS 0: per-row max of cos                          (fixed = I rows i)
// PASS 1: per-row sum of exp((10 - g_i*raw)/ln2)      (fixed = I rows i)
// PASS 2: per-row max over cols of (alpha_c - g_c*raw)(fixed = T rows j)
template <int PASS>
__global__ __launch_bounds__(256, 2) void k_gemm(const f16* __restrict__ A,
                                                 const f16* __restrict__ B,
                                                 const float* __restrict__ grow,
                                                 const float* __restrict__ alpha,
                                                 float* __restrict__ outP) {
    const int n = blockIdx.z, chunk = blockIdx.y, ft = blockIdx.x;
    const int tid = threadIdx.x, lane = tid & 63, wc = tid >> 6;
    const int quad = lane >> 4, lrow = lane & 15;

    __shared__ f16 Abuf[4][128 * 64];   // 64 KB persistent A tile (h-major)
    __shared__ float red[512];          // cross-wave reduction scratch

    const f16* At = A + ((size_t)n * SN + (size_t)ft * 128) * CN;

    // ---- prologue: stage entire A tile once (async DMA) ----
    #pragma unroll
    for (int h = 0; h < 4; ++h) stage64(At + h * 64, Abuf[h], tid);

    // A-fragment LDS offsets (halfs). Row ra = mt*16+lrow, and (ra&7)==(lrow&7)
    // so the XOR-swizzle term is mt-independent: addr = offA[kk] + mt*1024.
    int offA[2];
    #pragma unroll
    for (int kk = 0; kk < 2; ++kk)
        offA[kk] = lrow * 64 + (((kk * 4 + quad) ^ (lrow & 7)) * 8);

    // per-thread global B pointer: streamed row rb = wc*32 + nt*16 + lrow,
    // fragment bytes at (rb*CN + h*64 + kk*32 + quad*8) halfs. nt adds 16*CN.
    const f16* pB = B + ((size_t)n * SN + (size_t)chunk * (TPC * 128)
                         + wc * 32 + lrow) * CN + quad * 8;

    // PASS1 per-row exp coefficients (rows fixed for whole block).
    // a0 = (10-0.5g)*L2E = 10*L2E - a1, recomputed on the fly (saves 32 VGPR).
    const float L2E = 1.44269504089f;
    const float TENL2E = 14.4269504089f;
    float a1c[8][4];
    if constexpr (PASS == 1) {
        #pragma unroll
        for (int mt = 0; mt < 8; ++mt)
            #pragma unroll
            for (int v = 0; v < 4; ++v) {
                int r = ft * 128 + mt * 16 + quad * 4 + v;
                a1c[mt][v] = 0.5f * grow[(size_t)n * SN + r] * L2E;
            }
    }

    float runRow[8][4];
    #pragma unroll
    for (int mt = 0; mt < 8; ++mt)
        #pragma unroll
        for (int v = 0; v < 4; ++v) runRow[mt][v] = (PASS == 1) ? 0.f : -3.0e38f;

    float gl[2], al[2];

    // prefetch (t=0, h=0) into bfE before the barrier (drained by it, fine)
    f16x8 bfE[2][2], bfO[2][2];
    #pragma unroll
    for (int nt = 0; nt < 2; ++nt)
        #pragma unroll
        for (int kk = 0; kk < 2; ++kk)
            bfE[nt][kk] = *(const f16x8*)(pB + nt * (16 * CN) + kk * 32);

    __syncthreads();    // A tile landed; the ONLY barrier before the reduction

// one 64-K-half step: prefetch next half into BNXT (regs), MFMA from BCUR.
// h is a literal -> Abuf[h] and all indexing compile-time (rule #20).
#define HALF_STEP(h, BCUR, BNXT, NXTPTR)                                      \
    {                                                                         \
        _Pragma("unroll")                                                     \
        for (int nt = 0; nt < 2; ++nt)                                        \
            _Pragma("unroll")                                                 \
            for (int kk = 0; kk < 2; ++kk)                                    \
                BNXT[nt][kk] =                                                \
                    *(const f16x8*)((NXTPTR) + nt * (16 * CN) + kk * 32);     \
        _Pragma("unroll")                                                     \
        for (int kk = 0; kk < 2; ++kk) {                                      \
            f16x8 af[8];                                                      \
            _Pragma("unroll")                                                 \
            for (int mt = 0; mt < 8; ++mt)                                    \
                af[mt] = *(const f16x8*)&Abuf[h][offA[kk] + mt * 1024];       \
            _Pragma("unroll")                                                 \
            for (int mt = 0; mt < 8; ++mt)                                    \
                _Pragma("unroll")                                             \
                for (int nt = 0; nt < 2; ++nt)                                \
                    acc[mt][nt] = __builtin_amdgcn_mfma_f32_16x16x32_f16(     \
                        af[mt], BCUR[nt][kk], acc[mt][nt], 0, 0, 0);          \
        }                                                                     \
    }

    #pragma unroll 1
    for (int t = 0; t < TPC; ++t) {
        const f16* pBn = pB + 128 * CN;                    // next tile base
        const f16* pB1 = (t + 1 < TPC) ? pBn : pB;         // dummy on last

        if constexpr (PASS == 2) {
            // streamed-col coefficients (used in epilogue, loads hidden)
            #pragma unroll
            for (int nt = 0; nt < 2; ++nt) {
                int i = (chunk * TPC + t) * 128 + wc * 32 + nt * 16 + lrow;
                gl[nt] = grow[(size_t)n * SN + i];
                al[nt] = alpha[(size_t)n * SN + i];
            }
        }

        f32x4 acc[8][2];
        #pragma unroll
        for (int mt = 0; mt < 8; ++mt)
            #pragma unroll
            for (int nt = 0; nt < 2; ++nt) acc[mt][nt] = (f32x4){0.f, 0.f, 0.f, 0.f};

        HALF_STEP(0, bfE, bfO, pB + 64)
        HALF_STEP(1, bfO, bfE, pB + 128)
        HALF_STEP(2, bfE, bfO, pB + 192)
        HALF_STEP(3, bfO, bfE, pB1)
        // after h=3, bfE holds (t+1, h=0)

        // ---- per-tile epilogue (registers only) ----
        if constexpr (PASS == 0) {
            #pragma unroll
            for (int mt = 0; mt < 8; ++mt)
                #pragma unroll
                for (int v = 0; v < 4; ++v)
                    runRow[mt][v] = fmaxf(runRow[mt][v],
                                          fmaxf(acc[mt][0][v], acc[mt][1][v]));
        } else if constexpr (PASS == 1) {
            #pragma unroll
            for (int mt = 0; mt < 8; ++mt)
                #pragma unroll
                for (int v = 0; v < 4; ++v) {
                    float a1 = a1c[mt][v], a0 = TENL2E - a1;
                    float s = runRow[mt][v];
                    #pragma unroll
                    for (int nt = 0; nt < 2; ++nt) {
                        float arg = fminf(TENL2E, fmaf(acc[mt][nt][v], a1, a0));
                        s += exp2f(arg);
                    }
                    runRow[mt][v] = s;
                }
        } else {
            #pragma unroll
            for (int mt = 0; mt < 8; ++mt)
                #pragma unroll
                for (int v = 0; v < 4; ++v) {
                    #pragma unroll
                    for (int nt = 0; nt < 2; ++nt) {
                        float raw = fmaxf(0.f, fmaf(acc[mt][nt][v], -0.5f, 0.5f));
                        float lc = fmaf(-gl[nt], raw, al[nt]);
                        runRow[mt][v] = fmaxf(runRow[mt][v], lc);
                    }
                }
        }

        pB = pBn;
    }
#undef HALF_STEP

    // ---- cross-lane / cross-wave reduction ----
    #pragma unroll
    for (int mt = 0; mt < 8; ++mt)
        #pragma unroll
        for (int v = 0; v < 4; ++v) {
            float val = runRow[mt][v];
            #pragma unroll
            for (int d = 1; d < 16; d <<= 1) {
                float o = __shfl_xor(val, d, 64);
                val = (PASS == 1) ? (val + o) : fmaxf(val, o);
            }
            if (lrow == 0) red[wc * 128 + mt * 16 + quad * 4 + v] = val;
        }
    __syncthreads();
    if (tid < 128) {
        float a = red[tid], b = red[128 + tid];
        float c = red[256 + tid], d = red[384 + tid];
        float r = (PASS == 1) ? (a + b + c + d)
                              : fmaxf(fmaxf(a, b), fmaxf(c, d));
        outP[(size_t)(n * NCHUNK + chunk) * SN + ft * 128 + tid] = r;
    }
}

// ---------------- small reduce kernels (unchanged) ----------------

__global__ __launch_bounds__(256) void r_g(const float* __restrict__ rowmaxP,
                                           float* __restrict__ grow) {
    int idx = blockIdx.x * 256 + threadIdx.x;
    int n = idx / SN, i = idx - n * SN;
    float m = -3.0e38f;
    for (int ch = 0; ch < NCHUNK; ++ch)
        m = fmaxf(m, rowmaxP[(size_t)(n * NCHUNK + ch) * SN + i]);
    float mr = fmaxf(0.f, (1.f - m) * 0.5f);
    grow[idx] = 10.f / (mr + 1e-5f);
}

__global__ __launch_bounds__(256) void r_alpha(const float* __restrict__ rowsumP,
                                               float* __restrict__ alpha) {
    int idx = blockIdx.x * 256 + threadIdx.x;
    int n = idx / SN, i = idx - n * SN;
    float s = 0.f;
    for (int ch = 0; ch < NCHUNK; ++ch)
        s += rowsumP[(size_t)(n * NCHUNK + ch) * SN + i];
    alpha[idx] = 10.f - logf(s);
}

__global__ __launch_bounds__(256) void r_colfin(const float* __restrict__ colmaxP,
                                                float* __restrict__ bsum) {
    int idx = blockIdx.x * 256 + threadIdx.x;
    int n = idx / SN, j = idx - n * SN;
    float m = -3.0e38f;
    for (int ch = 0; ch < NCHUNK; ++ch)
        m = fmaxf(m, colmaxP[(size_t)(n * NCHUNK + ch) * SN + j]);
    float v = expf(m);
    #pragma unroll
    for (int d = 1; d < 64; d <<= 1) v += __shfl_xor(v, d, 64);
    __shared__ float sb[4];
    if ((threadIdx.x & 63) == 0) sb[threadIdx.x >> 6] = v;
    __syncthreads();
    if (threadIdx.x == 0) bsum[blockIdx.x] = sb[0] + sb[1] + sb[2] + sb[3];
}

__global__ __launch_bounds__(64) void r_loss(const float* __restrict__ bsum,
                                             float* __restrict__ out) {
    int t = threadIdx.x;
    float v = (t < 50) ? bsum[t] : 0.f;
    float v0 = (t < 25) ? v : 0.f;
    float v1 = (t >= 25 && t < 50) ? v : 0.f;
    #pragma unroll
    for (int d = 1; d < 64; d <<= 1) {
        v0 += __shfl_xor(v0, d, 64);
        v1 += __shfl_xor(v1, d, 64);
    }
    if (t == 0) {
        float cs0 = v0 * (1.0f / SN), cs1 = v1 * (1.0f / SN);
        out[0] = -0.5f * (logf(cs0) + logf(cs1));
    }
}

// ---------------- launch ----------------

extern "C" void kernel_launch(void* const* d_in, const int* in_sizes, int n_in,
                              void* d_out, int out_size, void* d_ws, size_t ws_size,
                              hipStream_t stream) {
    const float* I = (const float*)d_in[0];
    const float* T = (const float*)d_in[1];
    float* out = (float*)d_out;

    float* wsf = (float*)d_ws;
    float* meanT = wsf;                        // 256
    float* grow  = meanT + 256;                // 12800
    float* alpha = grow + 12800;               // 12800
    float* rowmaxP = alpha + 12800;            // 64000
    float* rowsumP = rowmaxP + 64000;          // 64000
    float* colmaxP = rowsumP + 64000;          // 64000
    float* bsum = colmaxP + 64000;             // 64
    f16* Ah = (f16*)(bsum + 64);               // 2*6400*256 fp16 (centered I, [n,s,c])
    f16* Bh = Ah + (size_t)NBATCH * SN * CN;   // centered T; total ws ~14.1 MB

    k_meanT<<<256, 256, 0, stream>>>(T, meanT);
    k_xpose<<<dim3(100, 8, 2), 256, 0, stream>>>(I, meanT, Ah);
    k_xpose<<<dim3(100, 8, 2), 256, 0, stream>>>(T, meanT, Bh);
    k_nrm<<<3200, 256, 0, stream>>>(Ah, Bh);

    dim3 gg(NTILES, NCHUNK, NBATCH);
    k_gemm<0><<<gg, 256, 0, stream>>>(Ah, Bh, nullptr, nullptr, rowmaxP);
    r_g<<<50, 256, 0, stream>>>(rowmaxP, grow);
    k_gemm<1><<<gg, 256, 0, stream>>>(Ah, Bh, grow, nullptr, rowsumP);
    r_alpha<<<50, 256, 0, stream>>>(rowsumP, alpha);
    k_gemm<2><<<gg, 256, 0, stream>>>(Bh, Ah, grow, alpha, colmaxP);
    r_colfin<<<50, 256, 0, stream>>>(colmaxP, bsum);
    r_loss<<<1, 64, 0, stream>>>(bsum, out);
}

// Round 3
// 242.817 us; speedup vs baseline: 2.4192x; 2.4192x over previous
//
#include <hip/hip_runtime.h>

#define SN 6400      // H*W
#define CN 256       // channels (= GEMM K)
#define NBATCH 2
#define NTILES 50    // SN / 128 (fixed-side row tiles)
#define NCHUNK 5     // streamed-side chunks (grid = 50*5*2 = 500 blocks)
#define TPC 5        // 256-wide streamed tiles per chunk

typedef _Float16 f16;
typedef f16 f16x8 __attribute__((ext_vector_type(8)));
typedef f16 f16x4 __attribute__((ext_vector_type(4)));
typedef float f32x4 __attribute__((ext_vector_type(4)));

__device__ __forceinline__ void gld16(const f16* g, f16* l) {
    __builtin_amdgcn_global_load_lds(
        (__attribute__((address_space(1))) void*)(g),
        (__attribute__((address_space(3))) void*)(l), 16, 0, 0);
}

// Stage a 256-row x 64-half (32 KB) K-chunk into LDS with 512 threads
// (4 gld16 per thread). LDS row = 64 halfs = 128 B = 8 x 16B chunks; chunk at
// LDS position c holds global chunk c ^ (row&7) (swizzle on the SOURCE
// address; the DMA lane->LDS map is fixed). Verified conflict-free (R1).
__device__ __forceinline__ void stageB(const f16* __restrict__ g,
                                       f16* l, int tid) {
    #pragma unroll
    for (int it = 0; it < 4; ++it) {
        int q = it * 512 + tid;
        int row = q >> 3, c = q & 7;
        int cg = c ^ (row & 7);
        gld16(g + (size_t)row * CN + cg * 8, l + (q & ~63) * 8);
    }
}

// ---------------- prep kernels (unchanged) ----------------

__global__ __launch_bounds__(256) void k_meanT(const float* __restrict__ T,
                                               float* __restrict__ meanT) {
    int c = blockIdx.x, t = threadIdx.x;
    const float* p0 = T + (size_t)c * SN;
    const float* p1 = T + (size_t)(CN + c) * SN;
    float s = 0.f;
    for (int i = t; i < SN; i += 256) s += p0[i] + p1[i];
    #pragma unroll
    for (int d = 1; d < 64; d <<= 1) s += __shfl_xor(s, d, 64);
    __shared__ float sb[4];
    if ((t & 63) == 0) sb[t >> 6] = s;
    __syncthreads();
    if (t == 0) meanT[c] = (sb[0] + sb[1] + sb[2] + sb[3]) * (1.0f / 12800.0f);
}

// transpose [n,c,s] -> [n,s,c], center, cast to fp16 (normalized by k_nrm)
__global__ __launch_bounds__(256) void k_xpose(const float* __restrict__ X,
                                               const float* __restrict__ meanT,
                                               f16* __restrict__ out) {
    int n = blockIdx.z, c0 = blockIdx.y * 32, s0 = blockIdx.x * 64;
    __shared__ float tile[32][65];
    int tx = threadIdx.x & 63, ty = threadIdx.x >> 6;
    const float* Xb = X + ((size_t)n * CN + c0) * SN + s0;
    #pragma unroll
    for (int cy = ty; cy < 32; cy += 4)
        tile[cy][tx] = Xb[(size_t)cy * SN + tx] - meanT[c0 + cy];
    __syncthreads();
    int cc = threadIdx.x & 31, sy = threadIdx.x >> 5;
    f16* ob = out + ((size_t)n * SN + s0) * CN + c0;
    #pragma unroll
    for (int sr = sy; sr < 64; sr += 8)
        ob[(size_t)sr * CN + cc] = (f16)tile[cc][sr];
}

// fused: per-row sum-of-squares -> rsqrt -> in-place scale (one wave per row)
__global__ __launch_bounds__(256) void k_nrm(f16* __restrict__ Ah,
                                             f16* __restrict__ Bh) {
    int w = threadIdx.x >> 6, lane = threadIdx.x & 63;
    int idx = blockIdx.x * 4 + w;
    f16x4* pa = (f16x4*)(Ah + (size_t)idx * CN + lane * 4);
    f16x4* pb = (f16x4*)(Bh + (size_t)idx * CN + lane * 4);
    f16x4 a = *pa, b = *pb;
    float sa = 0.f, sb = 0.f;
    #pragma unroll
    for (int j = 0; j < 4; ++j) {
        float x = (float)a[j]; sa += x * x;
        float y = (float)b[j]; sb += y * y;
    }
    #pragma unroll
    for (int d = 1; d < 64; d <<= 1) {
        sa += __shfl_xor(sa, d, 64);
        sb += __shfl_xor(sb, d, 64);
    }
    float ra = rsqrtf(sa), rb = rsqrtf(sb);
    #pragma unroll
    for (int j = 0; j < 4; ++j) {
        a[j] = (f16)((float)a[j] * ra);
        b[j] = (f16)((float)b[j] * rb);
    }
    *pa = a; *pb = b;
}

// ---------------- fused GEMM passes ----------------
// T3/T4 counted-vmcnt pipeline (plain HIP): 512 threads (8 waves, 2x4),
// A tile (128x256 halfs, 64 KB) persistent in LDS; B double-buffered
// 2 x 32 KB (BK=64 stages, 20 stages/block). Per stage:
//   compute(buf h&1) -> s_barrier -> issue DMA for stage s+2 into same buf
//   -> [tile epilogue at h==3] -> s_waitcnt vmcnt(4)  (waits ONLY stage s+1,
//   issued a full compute phase earlier) -> s_barrier.
// No vmcnt(0) drain in the main loop (that drain was the R0/R1 stall).
// LDS 128 KB -> 1 block/CU, 2 waves/SIMD; registers ~ R1 profile (no spill).
// PASS 0: per-row max of cos                          (fixed = I rows i)
// PASS 1: per-row sum of exp((10 - g_i*raw)/ln2)      (fixed = I rows i)
// PASS 2: per-row max over cols of (alpha_c - g_c*raw)(fixed = T rows j)
template <int PASS>
__global__ __launch_bounds__(512, 2) void k_gemm(const f16* __restrict__ A,
                                                 const f16* __restrict__ B,
                                                 const float* __restrict__ grow,
                                                 const float* __restrict__ alpha,
                                                 float* __restrict__ outP) {
    const int n = blockIdx.z, chunk = blockIdx.y, ft = blockIdx.x;
    const int tid = threadIdx.x, lane = tid & 63, wv = tid >> 6;
    const int wr = wv >> 2, wc = wv & 3, quad = lane >> 4, lrow = lane & 15;

    __shared__ f16 Abuf[4][128 * 64];   // 64 KB persistent A tile (h-major)
    __shared__ f16 Bb[2][256 * 64];     // 2 x 32 KB double-buffered B stage

    const f16* At = A + ((size_t)n * SN + (size_t)ft * 128) * CN;
    const f16* Bc = B + ((size_t)n * SN + (size_t)chunk * (TPC * 256)) * CN;

    // PASS1 per-row exp coefficients FIRST (oldest VMEM -> never forces a
    // drain of younger stage DMAs; compiler inserts its own wait before use)
    const float L2E = 1.44269504089f;
    const float TENL2E = 14.4269504089f;
    float a1c[4][4];
    if constexpr (PASS == 1) {
        #pragma unroll
        for (int mt = 0; mt < 4; ++mt)
            #pragma unroll
            for (int v = 0; v < 4; ++v) {
                int r = ft * 128 + wr * 64 + mt * 16 + quad * 4 + v;
                a1c[mt][v] = 0.5f * grow[(size_t)n * SN + r] * L2E;
            }
    }

    // ---- prologue: A tile (8 gld16/thread), then B stages 0 and 1 ----
    #pragma unroll
    for (int h = 0; h < 4; ++h) {
        #pragma unroll
        for (int it = 0; it < 2; ++it) {
            int q = it * 512 + tid;
            int row = q >> 3, c = q & 7;
            int cg = c ^ (row & 7);
            gld16(At + (size_t)row * CN + h * 64 + cg * 8,
                  Abuf[h] + (q & ~63) * 8);
        }
    }
    stageB(Bc, Bb[0], tid);         // stage 0 = (tile 0, h 0)
    stageB(Bc + 64, Bb[1], tid);    // stage 1 = (tile 0, h 1)

    // per-lane LDS read offsets (halfs), conflict-free via XOR swizzle
    int offA[4][2], offB[4][2];
    #pragma unroll
    for (int i = 0; i < 4; ++i) {
        int ra = wr * 64 + i * 16 + lrow;
        int rb = wc * 64 + i * 16 + lrow;
        #pragma unroll
        for (int kk = 0; kk < 2; ++kk) {
            offA[i][kk] = ra * 64 + (((kk * 4 + quad) ^ (ra & 7)) * 8);
            offB[i][kk] = rb * 64 + (((kk * 4 + quad) ^ (rb & 7)) * 8);
        }
    }

    float runRow[4][4];
    #pragma unroll
    for (int mt = 0; mt < 4; ++mt)
        #pragma unroll
        for (int v = 0; v < 4; ++v) runRow[mt][v] = (PASS == 1) ? 0.f : -3.0e38f;

    float gl[4], al[4];

    // outstanding: [a1c] + A(8) + S0(4) + S1(4); vmcnt(4) leaves only S1
    asm volatile("s_waitcnt vmcnt(4)" ::: "memory");
    __builtin_amdgcn_s_barrier();

#define BAR() __builtin_amdgcn_s_barrier()
#define WAIT4() asm volatile("s_waitcnt vmcnt(4)" ::: "memory")
#define WAIT0() asm volatile("s_waitcnt vmcnt(0)" ::: "memory")

// compute one 64-K stage from Abuf[h] x Bb[bi] (h, bi compile-time literals)
#define STAGE(h, bi)                                                      \
    { _Pragma("unroll")                                                   \
      for (int kk = 0; kk < 2; ++kk) {                                    \
          f16x8 af[4], bf[4];                                             \
          _Pragma("unroll")                                               \
          for (int mt = 0; mt < 4; ++mt)                                  \
              af[mt] = *(const f16x8*)&Abuf[h][offA[mt][kk]];             \
          _Pragma("unroll")                                               \
          for (int nt = 0; nt < 4; ++nt)                                  \
              bf[nt] = *(const f16x8*)&Bb[bi][offB[nt][kk]];              \
          _Pragma("unroll")                                               \
          for (int mt = 0; mt < 4; ++mt)                                  \
              _Pragma("unroll")                                           \
              for (int nt = 0; nt < 4; ++nt)                              \
                  acc[mt][nt] = __builtin_amdgcn_mfma_f32_16x16x32_f16(   \
                      af[mt], bf[nt], acc[mt][nt], 0, 0, 0);              \
      } }

// per-tile epilogue (registers only) — placed between DMA issue and WAIT4
#define EPILOGUE()                                                        \
    if constexpr (PASS == 0) {                                            \
        _Pragma("unroll")                                                 \
        for (int mt = 0; mt < 4; ++mt)                                    \
            _Pragma("unroll")                                             \
            for (int v = 0; v < 4; ++v) {                                 \
                float m = fmaxf(fmaxf(acc[mt][0][v], acc[mt][1][v]),      \
                                fmaxf(acc[mt][2][v], acc[mt][3][v]));     \
                runRow[mt][v] = fmaxf(runRow[mt][v], m);                  \
            }                                                             \
    } else if constexpr (PASS == 1) {                                     \
        _Pragma("unroll")                                                 \
        for (int mt = 0; mt < 4; ++mt)                                    \
            _Pragma("unroll")                                             \
            for (int v = 0; v < 4; ++v) {                                 \
                float a1 = a1c[mt][v], a0 = TENL2E - a1;                  \
                float s = runRow[mt][v];                                  \
                _Pragma("unroll")                                         \
                for (int nt = 0; nt < 4; ++nt) {                          \
                    float arg = fminf(TENL2E,                             \
                                      fmaf(acc[mt][nt][v], a1, a0));      \
                    s += exp2f(arg);                                      \
                }                                                         \
                runRow[mt][v] = s;                                        \
            }                                                             \
    } else {                                                              \
        _Pragma("unroll")                                                 \
        for (int mt = 0; mt < 4; ++mt)                                    \
            _Pragma("unroll")                                             \
            for (int v = 0; v < 4; ++v) {                                 \
                _Pragma("unroll")                                         \
                for (int nt = 0; nt < 4; ++nt) {                          \
                    float raw = fmaxf(0.f, fmaf(acc[mt][nt][v], -0.5f, 0.5f)); \
                    float lc = fmaf(-gl[nt], raw, al[nt]);                \
                    runRow[mt][v] = fmaxf(runRow[mt][v], lc);             \
                }                                                         \
            }                                                             \
    }

    f32x4 acc[4][4];

    #pragma unroll 1
    for (int t = 0; t < TPC - 1; ++t) {
        const f16* Bt = Bc + (size_t)t * (256 * CN);

        if constexpr (PASS == 2) {
            #pragma unroll
            for (int nt = 0; nt < 4; ++nt) {
                int i = (chunk * TPC + t) * 256 + wc * 64 + nt * 16 + lrow;
                gl[nt] = grow[(size_t)n * SN + i];
                al[nt] = alpha[(size_t)n * SN + i];
            }
        }

        #pragma unroll
        for (int mt = 0; mt < 4; ++mt)
            #pragma unroll
            for (int nt = 0; nt < 4; ++nt) acc[mt][nt] = (f32x4){0.f, 0.f, 0.f, 0.f};

        // stage s=4t+h; buffer = h&1; issue stage s+2 into the buffer just
        // read (all waves past BAR => safe); WAIT4 waits only for stage s+1.
        STAGE(0, 0) BAR(); stageB(Bt + 128, Bb[0], tid);            WAIT4(); BAR();
        STAGE(1, 1) BAR(); stageB(Bt + 192, Bb[1], tid);            WAIT4(); BAR();
        STAGE(2, 0) BAR(); stageB(Bt + 256 * CN, Bb[0], tid);       WAIT4(); BAR();
        STAGE(3, 1) BAR(); stageB(Bt + 256 * CN + 64, Bb[1], tid);
        EPILOGUE();                                                 WAIT4(); BAR();
    }

    // ---- peeled last tile (t = TPC-1): pipeline drain ----
    {
        const int t = TPC - 1;
        const f16* Bt = Bc + (size_t)t * (256 * CN);

        if constexpr (PASS == 2) {
            #pragma unroll
            for (int nt = 0; nt < 4; ++nt) {
                int i = (chunk * TPC + t) * 256 + wc * 64 + nt * 16 + lrow;
                gl[nt] = grow[(size_t)n * SN + i];
                al[nt] = alpha[(size_t)n * SN + i];
            }
        }

        #pragma unroll
        for (int mt = 0; mt < 4; ++mt)
            #pragma unroll
            for (int nt = 0; nt < 4; ++nt) acc[mt][nt] = (f32x4){0.f, 0.f, 0.f, 0.f};

        STAGE(0, 0) BAR(); stageB(Bt + 128, Bb[0], tid); WAIT4(); BAR();
        STAGE(1, 1) BAR(); stageB(Bt + 192, Bb[1], tid); WAIT4(); BAR();
        STAGE(2, 0) WAIT0(); BAR();      // only stage 19 outstanding
        STAGE(3, 1)
        EPILOGUE();
    }
#undef STAGE
#undef EPILOGUE
#undef BAR
#undef WAIT4
#undef WAIT0

    // ---- cross-lane / cross-wave reduction (red aliased onto Bb) ----
    __syncthreads();                 // all waves done reading Bb
    float* red = (float*)&Bb[0][0];
    #pragma unroll
    for (int mt = 0; mt < 4; ++mt)
        #pragma unroll
        for (int v = 0; v < 4; ++v) {
            float val = runRow[mt][v];
            #pragma unroll
            for (int d = 1; d < 16; d <<= 1) {
                float o = __shfl_xor(val, d, 64);
                val = (PASS == 1) ? (val + o) : fmaxf(val, o);
            }
            if (lrow == 0) red[wc * 128 + wr * 64 + mt * 16 + quad * 4 + v] = val;
        }
    __syncthreads();
    if (tid < 128) {
        float a = red[tid], b = red[128 + tid];
        float c = red[256 + tid], d = red[384 + tid];
        float r = (PASS == 1) ? (a + b + c + d)
                              : fmaxf(fmaxf(a, b), fmaxf(c, d));
        outP[(size_t)(n * NCHUNK + chunk) * SN + ft * 128 + tid] = r;
    }
}

// ---------------- small reduce kernels (unchanged) ----------------

__global__ __launch_bounds__(256) void r_g(const float* __restrict__ rowmaxP,
                                           float* __restrict__ grow) {
    int idx = blockIdx.x * 256 + threadIdx.x;
    int n = idx / SN, i = idx - n * SN;
    float m = -3.0e38f;
    for (int ch = 0; ch < NCHUNK; ++ch)
        m = fmaxf(m, rowmaxP[(size_t)(n * NCHUNK + ch) * SN + i]);
    float mr = fmaxf(0.f, (1.f - m) * 0.5f);
    grow[idx] = 10.f / (mr + 1e-5f);
}

__global__ __launch_bounds__(256) void r_alpha(const float* __restrict__ rowsumP,
                                               float* __restrict__ alpha) {
    int idx = blockIdx.x * 256 + threadIdx.x;
    int n = idx / SN, i = idx - n * SN;
    float s = 0.f;
    for (int ch = 0; ch < NCHUNK; ++ch)
        s += rowsumP[(size_t)(n * NCHUNK + ch) * SN + i];
    alpha[idx] = 10.f - logf(s);
}

__global__ __launch_bounds__(256) void r_colfin(const float* __restrict__ colmaxP,
                                                float* __restrict__ bsum) {
    int idx = blockIdx.x * 256 + threadIdx.x;
    int n = idx / SN, j = idx - n * SN;
    float m = -3.0e38f;
    for (int ch = 0; ch < NCHUNK; ++ch)
        m = fmaxf(m, colmaxP[(size_t)(n * NCHUNK + ch) * SN + j]);
    float v = expf(m);
    #pragma unroll
    for (int d = 1; d < 64; d <<= 1) v += __shfl_xor(v, d, 64);
    __shared__ float sb[4];
    if ((threadIdx.x & 63) == 0) sb[threadIdx.x >> 6] = v;
    __syncthreads();
    if (threadIdx.x == 0) bsum[blockIdx.x] = sb[0] + sb[1] + sb[2] + sb[3];
}

__global__ __launch_bounds__(64) void r_loss(const float* __restrict__ bsum,
                                             float* __restrict__ out) {
    int t = threadIdx.x;
    float v = (t < 50) ? bsum[t] : 0.f;
    float v0 = (t < 25) ? v : 0.f;
    float v1 = (t >= 25 && t < 50) ? v : 0.f;
    #pragma unroll
    for (int d = 1; d < 64; d <<= 1) {
        v0 += __shfl_xor(v0, d, 64);
        v1 += __shfl_xor(v1, d, 64);
    }
    if (t == 0) {
        float cs0 = v0 * (1.0f / SN), cs1 = v1 * (1.0f / SN);
        out[0] = -0.5f * (logf(cs0) + logf(cs1));
    }
}

// ---------------- launch ----------------

extern "C" void kernel_launch(void* const* d_in, const int* in_sizes, int n_in,
                              void* d_out, int out_size, void* d_ws, size_t ws_size,
                              hipStream_t stream) {
    const float* I = (const float*)d_in[0];
    const float* T = (const float*)d_in[1];
    float* out = (float*)d_out;

    float* wsf = (float*)d_ws;
    float* meanT = wsf;                        // 256
    float* grow  = meanT + 256;                // 12800
    float* alpha = grow + 12800;               // 12800
    float* rowmaxP = alpha + 12800;            // 64000
    float* rowsumP = rowmaxP + 64000;          // 64000
    float* colmaxP = rowsumP + 64000;          // 64000
    float* bsum = colmaxP + 64000;             // 64
    f16* Ah = (f16*)(bsum + 64);               // 2*6400*256 fp16 (centered I, [n,s,c])
    f16* Bh = Ah + (size_t)NBATCH * SN * CN;   // centered T; total ws ~14.1 MB

    k_meanT<<<256, 256, 0, stream>>>(T, meanT);
    k_xpose<<<dim3(100, 8, 2), 256, 0, stream>>>(I, meanT, Ah);
    k_xpose<<<dim3(100, 8, 2), 256, 0, stream>>>(T, meanT, Bh);
    k_nrm<<<3200, 256, 0, stream>>>(Ah, Bh);

    dim3 gg(NTILES, NCHUNK, NBATCH);
    k_gemm<0><<<gg, 512, 0, stream>>>(Ah, Bh, nullptr, nullptr, rowmaxP);
    r_g<<<50, 256, 0, stream>>>(rowmaxP, grow);
    k_gemm<1><<<gg, 512, 0, stream>>>(Ah, Bh, grow, nullptr, rowsumP);
    r_alpha<<<50, 256, 0, stream>>>(rowsumP, alpha);
    k_gemm<2><<<gg, 512, 0, stream>>>(Bh, Ah, grow, alpha, colmaxP);
    r_colfin<<<50, 256, 0, stream>>>(colmaxP, bsum);
    r_loss<<<1, 64, 0, stream>>>(bsum, out);
}